// Round 5
// baseline (603.415 us; speedup 1.0000x reference)
//
#include <hip/hip_runtime.h>
#include <math.h>

#define NNODES_FEAT 128   // node input dim
#define HD 128            // H*D = 4*32
#define H 4
#define D 32
#define EDGE_F 16         // edge input dim
#define NEG_SLOPE 0.2f

typedef _Float16 f16;
typedef _Float16 f16x2 __attribute__((ext_vector_type(2)));
typedef _Float16 f16x4 __attribute__((ext_vector_type(4)));
typedef _Float16 f16x8 __attribute__((ext_vector_type(8)));
typedef float f32x4 __attribute__((ext_vector_type(4)));

union ExPack { float2 f; f16x4 h; };

// ---------------- K0: w_eh[k][h] = sum_d W_edge[k*128 + h*32 + d] * attn_edge[h*32+d]
__global__ void k_wedge(const float* __restrict__ W_edge,
                        const float* __restrict__ attn_edge,
                        float* __restrict__ w_eh) {
    int t = threadIdx.x;            // 0..63
    int k = t >> 2;                 // 0..15
    int h = t & 3;                  // 0..3
    float s = 0.f;
    for (int d = 0; d < D; ++d)
        s += W_edge[k * HD + h * D + d] * attn_edge[h * D + d];
    w_eh[k * H + h] = s;
}

// ---------------- K0c: Wt[n][k] = (n<128 ? Wfc[k][n] : Wres[k][n-128]) as fp16
__global__ __launch_bounds__(256) void k_wt(const float* __restrict__ Wfc,
                                            const float* __restrict__ Wres,
                                            f16* __restrict__ Wt) {
    int i = blockIdx.x * 256 + threadIdx.x;    // 0..32767
    int n = i >> 7, k = i & 127;
    float v = (n < 128) ? Wfc[k * HD + n] : Wres[k * HD + (n - 128)];
    Wt[(size_t)n * 128 + k] = (f16)v;
}

// ---------------- K1: MFMA GEMM  A[N,128](fp32) @ Wt^T -> feat16 (cb=0) / out (cb=1)
#define LDK 136   // padded leading dim (halves)
__global__ __launch_bounds__(256) void k_gemm_mfma(
    const float* __restrict__ A, const f16* __restrict__ Wt,
    const float* __restrict__ bias, f16* __restrict__ feat16,
    float* __restrict__ out, int N) {
    __shared__ f16 As[64 * LDK];
    __shared__ f16 Bs[128 * LDK];
    int tid = threadIdx.x;
    int wave = tid >> 6, lane = tid & 63;
    int m0 = blockIdx.x * 64;
    int cb = blockIdx.y;

    // stage A tile: 64 rows x 128 floats, convert fp32->fp16 on LDS store
    for (int c = tid; c < 64 * 32; c += 256) {
        int r = c >> 5, cc = (c & 31) * 4;
        int gr = m0 + r;
        float4 v = make_float4(0.f, 0.f, 0.f, 0.f);
        if (gr < N) v = *(const float4*)(A + (size_t)gr * 128 + cc);
        f16x4 h = {(f16)v.x, (f16)v.y, (f16)v.z, (f16)v.w};
        *(f16x4*)(&As[r * LDK + cc]) = h;
    }
    const f16* Wblk = Wt + (size_t)cb * 128 * 128;
    for (int c = tid; c < 128 * 16; c += 256) {
        int r = c >> 4, cc = (c & 15) * 8;
        float4 v = *(const float4*)(Wblk + (size_t)r * 128 + cc);
        *(float4*)(&Bs[r * LDK + cc]) = v;
    }
    __syncthreads();

    int am = lane & 15, aq = lane >> 4;
    f32x4 acc[8];
#pragma unroll
    for (int nt = 0; nt < 8; ++nt) acc[nt] = (f32x4){0.f, 0.f, 0.f, 0.f};

    int arow = wave * 16 + am;
#pragma unroll
    for (int kc = 0; kc < 4; ++kc) {
        f16x8 a = *(const f16x8*)(&As[arow * LDK + kc * 32 + aq * 8]);
#pragma unroll
        for (int nt = 0; nt < 8; ++nt) {
            f16x8 b = *(const f16x8*)(&Bs[(nt * 16 + am) * LDK + kc * 32 + aq * 8]);
            acc[nt] = __builtin_amdgcn_mfma_f32_16x16x32_f16(a, b, acc[nt], 0, 0, 0);
        }
    }

    int orow0 = m0 + wave * 16 + aq * 4;
    if (cb == 0) {
#pragma unroll
        for (int nt = 0; nt < 8; ++nt) {
            int col = nt * 16 + am;
#pragma unroll
            for (int r = 0; r < 4; ++r) {
                int row = orow0 + r;
                if (row < N) feat16[(size_t)row * 128 + col] = (f16)acc[nt][r];
            }
        }
    } else {
#pragma unroll
        for (int nt = 0; nt < 8; ++nt) {
            int col = nt * 16 + am;
            float bv = bias[col];
#pragma unroll
            for (int r = 0; r < 4; ++r) {
                int row = orow0 + r;
                if (row < N) out[(size_t)row * 128 + col] = acc[nt][r] + bv;
            }
        }
    }
}

// ---------------- K1b: a_src/a_dst [N,H] reductions over feat16
__global__ __launch_bounds__(256) void k_attn_nodes(
    const f16* __restrict__ feat16, const float* __restrict__ attn_src,
    const float* __restrict__ attn_dst, float* __restrict__ a_src,
    float* __restrict__ a_dst, int N) {
    int g = blockIdx.x * 256 + threadIdx.x;
    int n = g >> 2, h = g & 3;
    if (n >= N) return;
    const f16* f = feat16 + (size_t)n * HD + h * D;
    const float* w1 = attn_src + h * D;
    const float* w2 = attn_dst + h * D;
    float s1 = 0.f, s2 = 0.f;
#pragma unroll
    for (int d = 0; d < D; d += 2) {
        f16x2 fv = *(const f16x2*)(f + d);
        float f0 = (float)fv.x, f1 = (float)fv.y;
        s1 += f0 * w1[d] + f1 * w1[d + 1];
        s2 += f0 * w2[d] + f1 * w2[d + 1];
    }
    a_src[n * H + h] = s1;
    a_dst[n * H + h] = s2;
}

// ---------------- K3a: streaming edge pass — ev -> recE[e] (coalesced) + degree count
__global__ __launch_bounds__(256) void k_fill_count(
    const float* __restrict__ edge_inputs, const int* __restrict__ src,
    const int* __restrict__ dst, const float* __restrict__ w_eh,
    const float* __restrict__ a_src, const float* __restrict__ a_dst,
    int* __restrict__ deg, float4* __restrict__ recE, int E) {
    __shared__ float weh_s[EDGE_F * H];
    if (threadIdx.x < EDGE_F * H) weh_s[threadIdx.x] = w_eh[threadIdx.x];
    __syncthreads();

    int base = blockIdx.x * 512 + threadIdx.x;
#pragma unroll
    for (int j = 0; j < 2; ++j) {
        int e = base + j * 256;
        if (e >= E) continue;

        const float* x = edge_inputs + (long)e * EDGE_F;
        float ae[H] = {0.f, 0.f, 0.f, 0.f};
#pragma unroll
        for (int k = 0; k < EDGE_F; ++k) {
            float xv = x[k];
#pragma unroll
            for (int h = 0; h < H; ++h) ae[h] += xv * weh_s[k * H + h];
        }
        int s = src[e], d = dst[e];
        float4 as = *(const float4*)(a_src + s * H);
        float4 ad = *(const float4*)(a_dst + d * H);
        float ev[H];
        ev[0] = as.x + ad.x + ae[0];
        ev[1] = as.y + ad.y + ae[1];
        ev[2] = as.z + ad.z + ae[2];
        ev[3] = as.w + ad.w + ae[3];
#pragma unroll
        for (int h = 0; h < H; ++h) {
            float t = ev[h];
            t = t > 0.f ? t : NEG_SLOPE * t;
            ev[h] = __expf(t);
        }
        ExPack p;
        p.h = (f16x4){(f16)ev[0], (f16)ev[1], (f16)ev[2], (f16)ev[3]};
        float4 r;
        r.x = __int_as_float(s);
        r.y = p.f.x;
        r.z = p.f.y;
        r.w = 0.f;
        recE[e] = r;                       // coalesced, e-order
        atomicAdd(deg + d, 1);
    }
}

// ---------------- K2b: scan, block partial sums (1024 elems / block)
__global__ __launch_bounds__(256) void k_scan_partial(
    const int* __restrict__ deg, int* __restrict__ partial, int N) {
    __shared__ int sdata[256];
    int t = threadIdx.x;
    int base = blockIdx.x * 1024 + t * 4;
    int s = 0;
#pragma unroll
    for (int j = 0; j < 4; ++j) { int i = base + j; if (i < N) s += deg[i]; }
    sdata[t] = s;
    __syncthreads();
    for (int off = 128; off > 0; off >>= 1) {
        if (t < off) sdata[t] += sdata[t + off];
        __syncthreads();
    }
    if (t == 0) partial[blockIdx.x] = sdata[0];
}

// ---------------- K2c: scan top level (single block), exclusive over partials
__global__ __launch_bounds__(256) void k_scan_top(
    int* __restrict__ partial, int* __restrict__ offs, int nb, int N) {
    __shared__ int sdata[256];
    int t = threadIdx.x;
    int v = (t < nb) ? partial[t] : 0;
    sdata[t] = v;
    __syncthreads();
    for (int off = 1; off < 256; off <<= 1) {
        int add = (t >= off) ? sdata[t - off] : 0;
        __syncthreads();
        sdata[t] += add;
        __syncthreads();
    }
    int excl = (t == 0) ? 0 : sdata[t - 1];
    if (t < nb) partial[t] = excl;
    if (t == nb - 1) offs[N] = sdata[t];   // total = E
}

// ---------------- K2d: final scan; offs aliases deg (in-place, block-local)
__global__ __launch_bounds__(256) void k_scan_final(
    int* __restrict__ deg_offs, const int* __restrict__ partial,
    int* __restrict__ cursor, int N) {
    __shared__ int sdata[256];
    int t = threadIdx.x;
    int base = blockIdx.x * 1024 + t * 4;
    int v[4]; int s = 0;
#pragma unroll
    for (int j = 0; j < 4; ++j) { int i = base + j; v[j] = (i < N) ? deg_offs[i] : 0; s += v[j]; }
    sdata[t] = s;
    __syncthreads();
    for (int off = 1; off < 256; off <<= 1) {
        int add = (t >= off) ? sdata[t - off] : 0;
        __syncthreads();
        sdata[t] += add;
        __syncthreads();
    }
    int excl = partial[blockIdx.x] + ((t == 0) ? 0 : sdata[t - 1]);
#pragma unroll
    for (int j = 0; j < 4; ++j) {
        int i = base + j;
        if (i < N) { deg_offs[i] = excl; cursor[i] = excl; excl += v[j]; }
    }
}

// ---------------- K3b: permutation builder — eidx[pos] = e (4B scatter)
__global__ __launch_bounds__(256) void k_perm(
    const int* __restrict__ dst, int* __restrict__ cursor,
    int* __restrict__ eidx, int E) {
    int base = blockIdx.x * 2048 + threadIdx.x;
#pragma unroll
    for (int j = 0; j < 8; ++j) {
        int e = base + j * 256;
        if (e < E) {
            int d = dst[e];
            int pos = atomicAdd(cursor + d, 1);
            eidx[pos] = e;
        }
    }
}

// ---------------- K4: per-dst aggregation; wave/node, lane = 2 adjacent cols
__global__ __launch_bounds__(256) void k_aggr(
    const f16* __restrict__ feat16, const float4* __restrict__ recE,
    const int* __restrict__ eidx, const int* __restrict__ offs,
    float* __restrict__ out, int N) {
    int wave = threadIdx.x >> 6;
    int lane = threadIdx.x & 63;
    int n = blockIdx.x * 4 + wave;
    if (n >= N) return;
    int beg = offs[n], end = offs[n + 1];
    if (end <= beg) return;                 // no in-edges: out keeps res+bias
    int h = lane >> 4;                      // head of cols {2l, 2l+1}
    size_t c0 = (size_t)2 * lane;
    float num0 = 0.f, num1 = 0.f, den = 0.f;
    int i = beg;
    for (; i + 3 < end; i += 4) {
        int e0 = eidx[i], e1 = eidx[i + 1], e2 = eidx[i + 2], e3 = eidx[i + 3];
        float4 r0 = recE[e0], r1 = recE[e1], r2 = recE[e2], r3 = recE[e3];
        int s0 = __float_as_int(r0.x), s1 = __float_as_int(r1.x);
        int s2 = __float_as_int(r2.x), s3 = __float_as_int(r3.x);
        f16x2 f0 = *(const f16x2*)(feat16 + (size_t)s0 * HD + c0);
        f16x2 f1 = *(const f16x2*)(feat16 + (size_t)s1 * HD + c0);
        f16x2 f2 = *(const f16x2*)(feat16 + (size_t)s2 * HD + c0);
        f16x2 f3 = *(const f16x2*)(feat16 + (size_t)s3 * HD + c0);
        ExPack p0, p1, p2, p3;
        p0.f = make_float2(r0.y, r0.z);
        p1.f = make_float2(r1.y, r1.z);
        p2.f = make_float2(r2.y, r2.z);
        p3.f = make_float2(r3.y, r3.z);
        float e0v = (float)p0.h[h], e1v = (float)p1.h[h];
        float e2v = (float)p2.h[h], e3v = (float)p3.h[h];
        num0 += e0v * (float)f0.x + e1v * (float)f1.x + e2v * (float)f2.x + e3v * (float)f3.x;
        num1 += e0v * (float)f0.y + e1v * (float)f1.y + e2v * (float)f2.y + e3v * (float)f3.y;
        den += e0v + e1v + e2v + e3v;
    }
    for (; i < end; ++i) {
        int e0 = eidx[i];
        float4 r0 = recE[e0];
        int s0 = __float_as_int(r0.x);
        f16x2 f0 = *(const f16x2*)(feat16 + (size_t)s0 * HD + c0);
        ExPack p0;
        p0.f = make_float2(r0.y, r0.z);
        float e0v = (float)p0.h[h];
        num0 += e0v * (float)f0.x;
        num1 += e0v * (float)f0.y;
        den += e0v;
    }
    float inv = 1.f / den;
    size_t o = (size_t)n * HD + c0;
    float2 v = *(float2*)(out + o);
    v.x += num0 * inv;
    v.y += num1 * inv;
    *(float2*)(out + o) = v;
}

extern "C" void kernel_launch(void* const* d_in, const int* in_sizes, int n_in,
                              void* d_out, int out_size, void* d_ws, size_t ws_size,
                              hipStream_t stream) {
    const float* node_inputs = (const float*)d_in[0];
    const float* edge_inputs = (const float*)d_in[1];
    const int*   src         = (const int*)d_in[2];
    const int*   dst         = (const int*)d_in[3];
    const float* W_fc        = (const float*)d_in[4];
    const float* attn_src_p  = (const float*)d_in[5];
    const float* attn_dst_p  = (const float*)d_in[6];
    const float* W_edge      = (const float*)d_in[7];
    const float* attn_edge_p = (const float*)d_in[8];
    const float* W_res       = (const float*)d_in[9];
    const float* bias_p      = (const float*)d_in[10];

    int N = in_sizes[0] / NNODES_FEAT;   // 100000
    int E = in_sizes[2];                 // 1600000

    float* out = (float*)d_out;

    // ---- workspace layout (recE 16B-aligned by construction) ----
    f16*    feat16  = (f16*)d_ws;                          // N*128 halves
    float4* recE    = (float4*)(feat16 + (size_t)N * HD);  // E * 16B, e-order
    int*    eidx    = (int*)(recE + (size_t)E);            // E (dst-bucketed)
    f16*    Wt      = (f16*)(eidx + (size_t)E);            // 256*128 halves
    float*  a_src   = (float*)(Wt + 256 * 128);            // N*4
    float*  a_dst   = a_src + (size_t)N * H;               // N*4
    float*  w_eh    = a_dst + (size_t)N * H;               // 64
    int*    deg     = (int*)(w_eh + 64);                   // N+2 (becomes offs)
    int*    offs    = deg;                                 // alias
    int*    cursor  = deg + (N + 2);                       // N
    int*    partial = cursor + N;                          // 128

    hipMemsetAsync(deg, 0, (size_t)(N + 2) * sizeof(int), stream);

    // precompute small tensors
    k_wedge<<<1, 64, 0, stream>>>(W_edge, attn_edge_p, w_eh);
    k_wt<<<(256 * 128) / 256, 256, 0, stream>>>(W_fc, W_res, Wt);

    // MFMA GEMM (stages fp32 A directly) -> feat16 (cb=0), out = res + bias (cb=1)
    dim3 g1((N + 63) / 64, 2);
    k_gemm_mfma<<<g1, 256, 0, stream>>>(node_inputs, Wt, bias_p, feat16, out, N);

    // per-node attention logits
    int nb = (N * H + 255) / 256;
    k_attn_nodes<<<nb, 256, 0, stream>>>(feat16, attn_src_p, attn_dst_p, a_src, a_dst, N);

    // streaming edge pass: ev -> recE (coalesced) + degree count
    int eb2 = (E + 511) / 512;
    k_fill_count<<<eb2, 256, 0, stream>>>(edge_inputs, src, dst, w_eh, a_src, a_dst,
                                          deg, recE, E);

    // CSR offsets
    int sb = (N + 1023) / 1024;   // 98 blocks
    k_scan_partial<<<sb, 256, 0, stream>>>(deg, partial, N);
    k_scan_top<<<1, 256, 0, stream>>>(partial, offs, sb, N);
    k_scan_final<<<sb, 256, 0, stream>>>(deg, partial, cursor, N);

    // permutation builder (4B scatter)
    int pb = (E + 2047) / 2048;
    k_perm<<<pb, 256, 0, stream>>>(dst, cursor, eidx, E);

    // aggregation via eidx indirection
    int ab = (N + 3) / 4;
    k_aggr<<<ab, 256, 0, stream>>>(feat16, recE, eidx, offs, out, N);
}

// Round 6
// 561.611 us; speedup vs baseline: 1.0744x; 1.0744x over previous
//
#include <hip/hip_runtime.h>
#include <math.h>

#define NNODES_FEAT 128   // node input dim
#define HD 128            // H*D = 4*32
#define H 4
#define D 32
#define EDGE_F 16         // edge input dim
#define NEG_SLOPE 0.2f

#define CB_SHIFT 9                       // coarse bucket = dst >> 9 (512 dst/bucket)
#define NBUCK 196                        // ceil(100000 / 512)
#define BH_STRIDE 16                     // bhist/gcur padded to one 64B line per counter

typedef _Float16 f16;
typedef _Float16 f16x2 __attribute__((ext_vector_type(2)));
typedef _Float16 f16x4 __attribute__((ext_vector_type(4)));
typedef _Float16 f16x8 __attribute__((ext_vector_type(8)));
typedef float f32x4 __attribute__((ext_vector_type(4)));

union ExPack { float2 f; f16x4 h; };

// ---------------- K0: w_eh[k][h] = sum_d W_edge[k*128 + h*32 + d] * attn_edge[h*32+d]
__global__ void k_wedge(const float* __restrict__ W_edge,
                        const float* __restrict__ attn_edge,
                        float* __restrict__ w_eh) {
    int t = threadIdx.x;            // 0..63
    int k = t >> 2;                 // 0..15
    int h = t & 3;                  // 0..3
    float s = 0.f;
    for (int d = 0; d < D; ++d)
        s += W_edge[k * HD + h * D + d] * attn_edge[h * D + d];
    w_eh[k * H + h] = s;
}

// ---------------- K0c: Wt[n][k] = (n<128 ? Wfc[k][n] : Wres[k][n-128]) as fp16
__global__ __launch_bounds__(256) void k_wt(const float* __restrict__ Wfc,
                                            const float* __restrict__ Wres,
                                            f16* __restrict__ Wt) {
    int i = blockIdx.x * 256 + threadIdx.x;    // 0..32767
    int n = i >> 7, k = i & 127;
    float v = (n < 128) ? Wfc[k * HD + n] : Wres[k * HD + (n - 128)];
    Wt[(size_t)n * 128 + k] = (f16)v;
}

// ---------------- K1: MFMA GEMM  A[N,128](fp32) @ Wt^T -> feat16 (cb=0) / out (cb=1)
#define LDK 136   // padded leading dim (halves)
__global__ __launch_bounds__(256) void k_gemm_mfma(
    const float* __restrict__ A, const f16* __restrict__ Wt,
    const float* __restrict__ bias, f16* __restrict__ feat16,
    float* __restrict__ out, int N) {
    __shared__ f16 As[64 * LDK];
    __shared__ f16 Bs[128 * LDK];
    int tid = threadIdx.x;
    int wave = tid >> 6, lane = tid & 63;
    int m0 = blockIdx.x * 64;
    int cb = blockIdx.y;

    for (int c = tid; c < 64 * 32; c += 256) {
        int r = c >> 5, cc = (c & 31) * 4;
        int gr = m0 + r;
        float4 v = make_float4(0.f, 0.f, 0.f, 0.f);
        if (gr < N) v = *(const float4*)(A + (size_t)gr * 128 + cc);
        f16x4 h = {(f16)v.x, (f16)v.y, (f16)v.z, (f16)v.w};
        *(f16x4*)(&As[r * LDK + cc]) = h;
    }
    const f16* Wblk = Wt + (size_t)cb * 128 * 128;
    for (int c = tid; c < 128 * 16; c += 256) {
        int r = c >> 4, cc = (c & 15) * 8;
        float4 v = *(const float4*)(Wblk + (size_t)r * 128 + cc);
        *(float4*)(&Bs[r * LDK + cc]) = v;
    }
    __syncthreads();

    int am = lane & 15, aq = lane >> 4;
    f32x4 acc[8];
#pragma unroll
    for (int nt = 0; nt < 8; ++nt) acc[nt] = (f32x4){0.f, 0.f, 0.f, 0.f};

    int arow = wave * 16 + am;
#pragma unroll
    for (int kc = 0; kc < 4; ++kc) {
        f16x8 a = *(const f16x8*)(&As[arow * LDK + kc * 32 + aq * 8]);
#pragma unroll
        for (int nt = 0; nt < 8; ++nt) {
            f16x8 b = *(const f16x8*)(&Bs[(nt * 16 + am) * LDK + kc * 32 + aq * 8]);
            acc[nt] = __builtin_amdgcn_mfma_f32_16x16x32_f16(a, b, acc[nt], 0, 0, 0);
        }
    }

    int orow0 = m0 + wave * 16 + aq * 4;
    if (cb == 0) {
#pragma unroll
        for (int nt = 0; nt < 8; ++nt) {
            int col = nt * 16 + am;
#pragma unroll
            for (int r = 0; r < 4; ++r) {
                int row = orow0 + r;
                if (row < N) feat16[(size_t)row * 128 + col] = (f16)acc[nt][r];
            }
        }
    } else {
#pragma unroll
        for (int nt = 0; nt < 8; ++nt) {
            int col = nt * 16 + am;
            float bv = bias[col];
#pragma unroll
            for (int r = 0; r < 4; ++r) {
                int row = orow0 + r;
                if (row < N) out[(size_t)row * 128 + col] = acc[nt][r] + bv;
            }
        }
    }
}

// ---------------- K1b: a_src/a_dst [N,H] reductions over feat16
__global__ __launch_bounds__(256) void k_attn_nodes(
    const f16* __restrict__ feat16, const float* __restrict__ attn_src,
    const float* __restrict__ attn_dst, float* __restrict__ a_src,
    float* __restrict__ a_dst, int N) {
    int g = blockIdx.x * 256 + threadIdx.x;
    int n = g >> 2, h = g & 3;
    if (n >= N) return;
    const f16* f = feat16 + (size_t)n * HD + h * D;
    const float* w1 = attn_src + h * D;
    const float* w2 = attn_dst + h * D;
    float s1 = 0.f, s2 = 0.f;
#pragma unroll
    for (int d = 0; d < D; d += 2) {
        f16x2 fv = *(const f16x2*)(f + d);
        float f0 = (float)fv.x, f1 = (float)fv.y;
        s1 += f0 * w1[d] + f1 * w1[d + 1];
        s2 += f0 * w2[d] + f1 * w2[d + 1];
    }
    a_src[n * H + h] = s1;
    a_dst[n * H + h] = s2;
}

// ---------------- K3a: streaming edge pass — recE[e] (coalesced) + deg + coarse hist
__global__ __launch_bounds__(256) void k_fill_count(
    const float* __restrict__ edge_inputs, const int* __restrict__ src,
    const int* __restrict__ dst, const float* __restrict__ w_eh,
    const float* __restrict__ a_src, const float* __restrict__ a_dst,
    int* __restrict__ deg, int* __restrict__ bhist,
    float4* __restrict__ recE, int E) {
    __shared__ float weh_s[EDGE_F * H];
    __shared__ int hist[NBUCK];
    if (threadIdx.x < EDGE_F * H) weh_s[threadIdx.x] = w_eh[threadIdx.x];
    if (threadIdx.x < NBUCK) hist[threadIdx.x] = 0;
    __syncthreads();

    int base = blockIdx.x * 512 + threadIdx.x;
#pragma unroll
    for (int j = 0; j < 2; ++j) {
        int e = base + j * 256;
        if (e >= E) continue;

        const float* x = edge_inputs + (long)e * EDGE_F;
        float ae[H] = {0.f, 0.f, 0.f, 0.f};
#pragma unroll
        for (int k = 0; k < EDGE_F; ++k) {
            float xv = x[k];
#pragma unroll
            for (int h = 0; h < H; ++h) ae[h] += xv * weh_s[k * H + h];
        }
        int s = src[e], d = dst[e];
        float4 as = *(const float4*)(a_src + s * H);
        float4 ad = *(const float4*)(a_dst + d * H);
        float ev[H];
        ev[0] = as.x + ad.x + ae[0];
        ev[1] = as.y + ad.y + ae[1];
        ev[2] = as.z + ad.z + ae[2];
        ev[3] = as.w + ad.w + ae[3];
#pragma unroll
        for (int h = 0; h < H; ++h) {
            float t = ev[h];
            t = t > 0.f ? t : NEG_SLOPE * t;
            ev[h] = __expf(t);
        }
        ExPack p;
        p.h = (f16x4){(f16)ev[0], (f16)ev[1], (f16)ev[2], (f16)ev[3]};
        float4 r;
        r.x = __int_as_float(s);
        r.y = p.f.x;
        r.z = p.f.y;
        r.w = 0.f;
        recE[e] = r;                       // coalesced, e-order
        atomicAdd(deg + d, 1);
        atomicAdd(&hist[d >> CB_SHIFT], 1);
    }
    __syncthreads();
    if (threadIdx.x < NBUCK && hist[threadIdx.x] > 0)
        atomicAdd(bhist + threadIdx.x * BH_STRIDE, hist[threadIdx.x]);
}

// ---------------- K2b: scan, block partial sums (1024 elems / block)
__global__ __launch_bounds__(256) void k_scan_partial(
    const int* __restrict__ deg, int* __restrict__ partial, int N) {
    __shared__ int sdata[256];
    int t = threadIdx.x;
    int base = blockIdx.x * 1024 + t * 4;
    int s = 0;
#pragma unroll
    for (int j = 0; j < 4; ++j) { int i = base + j; if (i < N) s += deg[i]; }
    sdata[t] = s;
    __syncthreads();
    for (int off = 128; off > 0; off >>= 1) {
        if (t < off) sdata[t] += sdata[t + off];
        __syncthreads();
    }
    if (t == 0) partial[blockIdx.x] = sdata[0];
}

// ---------------- K2c: scan top level (single block), exclusive over partials
__global__ __launch_bounds__(256) void k_scan_top(
    int* __restrict__ partial, int* __restrict__ offs, int nb, int N) {
    __shared__ int sdata[256];
    int t = threadIdx.x;
    int v = (t < nb) ? partial[t] : 0;
    sdata[t] = v;
    __syncthreads();
    for (int off = 1; off < 256; off <<= 1) {
        int add = (t >= off) ? sdata[t - off] : 0;
        __syncthreads();
        sdata[t] += add;
        __syncthreads();
    }
    int excl = (t == 0) ? 0 : sdata[t - 1];
    if (t < nb) partial[t] = excl;
    if (t == nb - 1) offs[N] = sdata[t];   // total = E
}

// ---------------- K2d: final scan; offs aliases deg (in-place, block-local)
__global__ __launch_bounds__(256) void k_scan_final(
    int* __restrict__ deg_offs, const int* __restrict__ partial, int N) {
    __shared__ int sdata[256];
    int t = threadIdx.x;
    int base = blockIdx.x * 1024 + t * 4;
    int v[4]; int s = 0;
#pragma unroll
    for (int j = 0; j < 4; ++j) { int i = base + j; v[j] = (i < N) ? deg_offs[i] : 0; s += v[j]; }
    sdata[t] = s;
    __syncthreads();
    for (int off = 1; off < 256; off <<= 1) {
        int add = (t >= off) ? sdata[t - off] : 0;
        __syncthreads();
        sdata[t] += add;
        __syncthreads();
    }
    int excl = partial[blockIdx.x] + ((t == 0) ? 0 : sdata[t - 1]);
#pragma unroll
    for (int j = 0; j < 4; ++j) {
        int i = base + j;
        if (i < N) { deg_offs[i] = excl; excl += v[j]; }
    }
}

// ---------------- K2e: scan coarse-bucket hist -> bbase (exclusive) + init gcur
__global__ __launch_bounds__(256) void k_bscan(
    const int* __restrict__ bhist, int* __restrict__ bbase,
    int* __restrict__ gcur) {
    __shared__ int sdata[256];
    int t = threadIdx.x;
    int v = (t < NBUCK) ? bhist[t * BH_STRIDE] : 0;
    sdata[t] = v;
    __syncthreads();
    for (int off = 1; off < 256; off <<= 1) {
        int add = (t >= off) ? sdata[t - off] : 0;
        __syncthreads();
        sdata[t] += add;
        __syncthreads();
    }
    int excl = (t == 0) ? 0 : sdata[t - 1];
    if (t < NBUCK) {
        bbase[t] = excl;
        gcur[t * BH_STRIDE] = excl;
    }
    if (t == NBUCK - 1) bbase[NBUCK] = sdata[t];   // = E
}

// ---------------- K3b: coarse partition — ebuck[pos] = e, bucketed by dst>>9
__global__ __launch_bounds__(256) void k_part_coarse(
    const int* __restrict__ dst, int* __restrict__ gcur,
    int* __restrict__ ebuck, int E) {
    __shared__ int hist[NBUCK];
    __shared__ int curl[NBUCK];
    int t = threadIdx.x;
    if (t < NBUCK) hist[t] = 0;
    __syncthreads();

    int base = blockIdx.x * 4096;
#pragma unroll
    for (int j = 0; j < 16; ++j) {
        int e = base + j * 256 + t;
        if (e < E) atomicAdd(&hist[dst[e] >> CB_SHIFT], 1);
    }
    __syncthreads();
    if (t < NBUCK && hist[t] > 0)
        curl[t] = atomicAdd(&gcur[t * BH_STRIDE], hist[t]);
    __syncthreads();
#pragma unroll
    for (int j = 0; j < 16; ++j) {
        int e = base + j * 256 + t;
        if (e < E) {
            int b = dst[e] >> CB_SHIFT;
            int pos = atomicAdd(&curl[b], 1);
            ebuck[pos] = e;
        }
    }
}

// ---------------- K3c: fine partition — rec_sorted[csr_pos] = recE[e]
// one block per coarse bucket; writes land in the block's exclusive window
__global__ __launch_bounds__(1024) void k_part_fine(
    const int* __restrict__ dst, const int* __restrict__ ebuck,
    const int* __restrict__ bbase, const int* __restrict__ offs,
    const float4* __restrict__ recE, float4* __restrict__ rec_sorted, int N) {
    __shared__ int cur[1 << CB_SHIFT];
    int t = threadIdx.x;
    int b = blockIdx.x;
    int dbase = b << CB_SHIFT;
    if (t < (1 << CB_SHIFT)) {
        int idx = dbase + t;
        cur[t] = offs[idx < N ? idx : N];
    }
    __syncthreads();
    int beg = bbase[b], end = bbase[b + 1];
    for (int i = beg + t; i < end; i += 1024) {
        int e = ebuck[i];
        int d = dst[e];
        int pos = atomicAdd(&cur[d - dbase], 1);
        rec_sorted[pos] = recE[e];
    }
}

// ---------------- K4: per-dst aggregation; wave/node, lane = 2 adjacent cols
__global__ __launch_bounds__(256) void k_aggr(
    const f16* __restrict__ feat16, const float4* __restrict__ rec,
    const int* __restrict__ offs, float* __restrict__ out, int N) {
    int wave = threadIdx.x >> 6;
    int lane = threadIdx.x & 63;
    int n = blockIdx.x * 4 + wave;
    if (n >= N) return;
    int beg = offs[n], end = offs[n + 1];
    if (end <= beg) return;                 // no in-edges: out keeps res+bias
    int h = lane >> 4;                      // head of cols {2l, 2l+1}
    size_t c0 = (size_t)2 * lane;
    float num0 = 0.f, num1 = 0.f, den = 0.f;
    int i = beg;
    for (; i + 3 < end; i += 4) {
        float4 r0 = rec[i], r1 = rec[i + 1], r2 = rec[i + 2], r3 = rec[i + 3];
        int s0 = __float_as_int(r0.x), s1 = __float_as_int(r1.x);
        int s2 = __float_as_int(r2.x), s3 = __float_as_int(r3.x);
        f16x2 f0 = *(const f16x2*)(feat16 + (size_t)s0 * HD + c0);
        f16x2 f1 = *(const f16x2*)(feat16 + (size_t)s1 * HD + c0);
        f16x2 f2 = *(const f16x2*)(feat16 + (size_t)s2 * HD + c0);
        f16x2 f3 = *(const f16x2*)(feat16 + (size_t)s3 * HD + c0);
        ExPack p0, p1, p2, p3;
        p0.f = make_float2(r0.y, r0.z);
        p1.f = make_float2(r1.y, r1.z);
        p2.f = make_float2(r2.y, r2.z);
        p3.f = make_float2(r3.y, r3.z);
        float e0 = (float)p0.h[h], e1 = (float)p1.h[h];
        float e2 = (float)p2.h[h], e3 = (float)p3.h[h];
        num0 += e0 * (float)f0.x + e1 * (float)f1.x + e2 * (float)f2.x + e3 * (float)f3.x;
        num1 += e0 * (float)f0.y + e1 * (float)f1.y + e2 * (float)f2.y + e3 * (float)f3.y;
        den += e0 + e1 + e2 + e3;
    }
    for (; i < end; ++i) {
        float4 r0 = rec[i];
        int s0 = __float_as_int(r0.x);
        f16x2 f0 = *(const f16x2*)(feat16 + (size_t)s0 * HD + c0);
        ExPack p0;
        p0.f = make_float2(r0.y, r0.z);
        float e0 = (float)p0.h[h];
        num0 += e0 * (float)f0.x;
        num1 += e0 * (float)f0.y;
        den += e0;
    }
    float inv = 1.f / den;
    size_t o = (size_t)n * HD + c0;
    float2 v = *(float2*)(out + o);
    v.x += num0 * inv;
    v.y += num1 * inv;
    *(float2*)(out + o) = v;
}

extern "C" void kernel_launch(void* const* d_in, const int* in_sizes, int n_in,
                              void* d_out, int out_size, void* d_ws, size_t ws_size,
                              hipStream_t stream) {
    const float* node_inputs = (const float*)d_in[0];
    const float* edge_inputs = (const float*)d_in[1];
    const int*   src         = (const int*)d_in[2];
    const int*   dst         = (const int*)d_in[3];
    const float* W_fc        = (const float*)d_in[4];
    const float* attn_src_p  = (const float*)d_in[5];
    const float* attn_dst_p  = (const float*)d_in[6];
    const float* W_edge      = (const float*)d_in[7];
    const float* attn_edge_p = (const float*)d_in[8];
    const float* W_res       = (const float*)d_in[9];
    const float* bias_p      = (const float*)d_in[10];

    int N = in_sizes[0] / NNODES_FEAT;   // 100000
    int E = in_sizes[2];                 // 1600000

    float* out = (float*)d_out;

    // ---- workspace layout (16B-aligned segments first) ----
    f16*    feat16     = (f16*)d_ws;                            // N*128 halves
    float4* recE       = (float4*)(feat16 + (size_t)N * HD);    // E * 16B, e-order
    float4* rec_sorted = recE + (size_t)E;                      // E * 16B, CSR order
    int*    ebuck      = (int*)(rec_sorted + (size_t)E);        // E
    f16*    Wt         = (f16*)(ebuck + (size_t)E);             // 256*128 halves
    float*  a_src      = (float*)(Wt + 256 * 128);              // N*4
    float*  a_dst      = a_src + (size_t)N * H;                 // N*4
    float*  w_eh       = a_dst + (size_t)N * H;                 // 64
    int*    deg        = (int*)(w_eh + 64);                     // N+2 (becomes offs)
    int*    offs       = deg;                                   // alias
    int*    bhist      = deg + (N + 2);                         // NBUCK*BH_STRIDE
    int*    gcur       = bhist + NBUCK * BH_STRIDE;             // NBUCK*BH_STRIDE
    int*    bbase      = gcur + NBUCK * BH_STRIDE;              // NBUCK+1
    int*    partial    = bbase + (NBUCK + 4);                   // 128

    // zero deg + bhist (contiguous)
    hipMemsetAsync(deg, 0, (size_t)(N + 2 + NBUCK * BH_STRIDE) * sizeof(int), stream);

    // precompute small tensors
    k_wedge<<<1, 64, 0, stream>>>(W_edge, attn_edge_p, w_eh);
    k_wt<<<(256 * 128) / 256, 256, 0, stream>>>(W_fc, W_res, Wt);

    // MFMA GEMM -> feat16 (cb=0), out = res + bias (cb=1)
    dim3 g1((N + 63) / 64, 2);
    k_gemm_mfma<<<g1, 256, 0, stream>>>(node_inputs, Wt, bias_p, feat16, out, N);

    // per-node attention logits
    int nb = (N * H + 255) / 256;
    k_attn_nodes<<<nb, 256, 0, stream>>>(feat16, attn_src_p, attn_dst_p, a_src, a_dst, N);

    // streaming edge pass: recE (coalesced) + deg + coarse hist
    int eb2 = (E + 511) / 512;
    k_fill_count<<<eb2, 256, 0, stream>>>(edge_inputs, src, dst, w_eh, a_src, a_dst,
                                          deg, bhist, recE, E);

    // CSR offsets over dst
    int sb = (N + 1023) / 1024;   // 98 blocks
    k_scan_partial<<<sb, 256, 0, stream>>>(deg, partial, N);
    k_scan_top<<<1, 256, 0, stream>>>(partial, offs, sb, N);
    k_scan_final<<<sb, 256, 0, stream>>>(deg, partial, N);

    // coarse-bucket offsets + cursors
    k_bscan<<<1, 256, 0, stream>>>(bhist, bbase, gcur);

    // two-phase partition into CSR record order
    int cb = (E + 4095) / 4096;   // 391 blocks
    k_part_coarse<<<cb, 256, 0, stream>>>(dst, gcur, ebuck, E);
    k_part_fine<<<NBUCK, 1024, 0, stream>>>(dst, ebuck, bbase, offs, recE, rec_sorted, N);

    // aggregation (sequential records)
    int ab = (N + 3) / 4;
    k_aggr<<<ab, 256, 0, stream>>>(feat16, rec_sorted, offs, out, N);
}